// Round 2
// baseline (287.660 us; speedup 1.0000x reference)
//
#include <hip/hip_runtime.h>

#define B_    4
#define CIN_  64
#define COUT_ 64
#define N_    16384
#define K_    8

// ---------------------------------------------------------------------------
// Main kernel: per (b, 128-point tile): dense per-point matvec
//   acc[n][o] = (ft0, ft1, ft2, fb) then scatter contrib into ws[b][j][o]
// Block = 256 threads (4 waves), lane = o. Each wave owns 16 points per tile.
// ---------------------------------------------------------------------------
__global__ __launch_bounds__(256, 2) void flexconv_main(
    const float* __restrict__ feat,    // [B, CIN, N]
    const float* __restrict__ theta,   // [3, CIN, COUT]
    const float* __restrict__ wbias,   // [CIN, COUT]
    const int*   __restrict__ nbh,     // [B, K, N]
    const float* __restrict__ pos,     // [B, 3, N]
    float*       __restrict__ ws)      // [B, N, COUT]
{
    __shared__ float4 Wl[CIN_ * COUT_];   // 64 KiB: (t0,t1,t2,wb) per (i,o)
    __shared__ float  Fl[CIN_ * 64];      // 16 KiB feature tile [i][nn]

    const int tid  = threadIdx.x;
    const int lane = tid & 63;            // o
    const int w    = tid >> 6;            // wave 0..3

    const int b     = blockIdx.x >> 7;            // 128 blocks per batch
    const int nbase = (blockIdx.x & 127) << 7;    // *128

    // Stage interleaved weights (once per block).
    for (int e = tid; e < CIN_ * COUT_; e += 256) {
        const int i = e >> 6, o = e & 63;
        Wl[e] = make_float4(theta[0 * 4096 + i * 64 + o],
                            theta[1 * 4096 + i * 64 + o],
                            theta[2 * 4096 + i * 64 + o],
                            wbias[i * 64 + o]);
    }

    const float* featb = feat + (size_t)b * CIN_ * N_;
    const float* posb  = pos  + (size_t)b * 3 * N_;
    const int*   nbhb  = nbh  + (size_t)b * K_ * N_;
    float*       wsb   = ws   + (size_t)b * N_ * COUT_;

    for (int t = 0; t < 2; ++t) {
        const int n0 = nbase + t * 64;

        __syncthreads();   // Wl ready / previous tile's Fl readers done
        // Stage feature tile with float4 (coalesced): Fl[i][0..63] = feat[i][n0..n0+63]
        for (int it = 0; it < 4; ++it) {
            const int e = it * 256 + tid;       // 0..1023
            const int i = e >> 4, c = e & 15;
            ((float4*)Fl)[i * 16 + c] = *(const float4*)&featb[(size_t)i * N_ + n0 + 4 * c];
        }
        __syncthreads();

        const int pbase = w * 16;   // this wave's 16 points
        float4 acc[16];
        #pragma unroll
        for (int j = 0; j < 16; ++j) acc[j] = make_float4(0.f, 0.f, 0.f, 0.f);

        #pragma unroll 2
        for (int i = 0; i < CIN_; ++i) {
            const float4 wv = Wl[i * 64 + lane];                       // ds_read_b128
            const float4 f0 = *(const float4*)&Fl[i * 64 + pbase + 0]; // b128 broadcast
            const float4 f1 = *(const float4*)&Fl[i * 64 + pbase + 4];
            const float4 f2 = *(const float4*)&Fl[i * 64 + pbase + 8];
            const float4 f3 = *(const float4*)&Fl[i * 64 + pbase + 12];
            #define ACC1(J, FS) \
                acc[J].x = fmaf(wv.x, FS, acc[J].x); \
                acc[J].y = fmaf(wv.y, FS, acc[J].y); \
                acc[J].z = fmaf(wv.z, FS, acc[J].z); \
                acc[J].w = fmaf(wv.w, FS, acc[J].w);
            ACC1(0,  f0.x) ACC1(1,  f0.y) ACC1(2,  f0.z) ACC1(3,  f0.w)
            ACC1(4,  f1.x) ACC1(5,  f1.y) ACC1(6,  f1.z) ACC1(7,  f1.w)
            ACC1(8,  f2.x) ACC1(9,  f2.y) ACC1(10, f2.z) ACC1(11, f2.w)
            ACC1(12, f3.x) ACC1(13, f3.y) ACC1(14, f3.z) ACC1(15, f3.w)
            #undef ACC1
        }

        // Scatter phase: 16 points × 8 neighbors, contiguous 256B atomic per (point,k)
        #pragma unroll 1
        for (int j = 0; j < 16; ++j) {
            const int n = n0 + pbase + j;
            const float px = posb[n];
            const float py = posb[N_ + n];
            const float pz = posb[2 * N_ + n];
            const float4 a = acc[j];
            #pragma unroll
            for (int k = 0; k < K_; ++k) {
                const int idx = nbhb[k * N_ + n];
                const float dx = posb[idx]          - px;
                const float dy = posb[N_ + idx]     - py;
                const float dz = posb[2 * N_ + idx] - pz;
                const float c  = fmaf(dx, a.x, fmaf(dy, a.y, fmaf(dz, a.z, a.w)));
                atomicAdd(&wsb[(size_t)idx * COUT_ + lane], c);
            }
        }
    }
}

// ---------------------------------------------------------------------------
// Finish: out[b][o][n] = ws[b][n][o] + bias[o].  256n × 64o tile per block.
// ---------------------------------------------------------------------------
__global__ __launch_bounds__(256) void flexconv_finish(
    const float* __restrict__ ws,
    const float* __restrict__ bias,
    float*       __restrict__ out)
{
    __shared__ float T[256][65];
    const int tid = threadIdx.x;
    const int b   = blockIdx.x >> 6;           // 64 tiles per batch
    const int n0  = (blockIdx.x & 63) << 8;    // *256

    const float* wsb = ws + (size_t)b * N_ * COUT_;
    const int r = tid >> 4, c = tid & 15;
    for (int it = 0; it < 16; ++it) {
        const int n = it * 16 + r;
        const float4 v = *(const float4*)&wsb[(size_t)(n0 + n) * COUT_ + c * 4];
        T[n][c * 4 + 0] = v.x;
        T[n][c * 4 + 1] = v.y;
        T[n][c * 4 + 2] = v.z;
        T[n][c * 4 + 3] = v.w;
    }
    __syncthreads();

    float* outb = out + (size_t)b * COUT_ * N_;
    const int l = tid & 63, q = tid >> 6;
    for (int it = 0; it < 16; ++it) {
        const int o  = it * 4 + q;
        const float bo = bias[o];
        float* orow = outb + (size_t)o * N_ + n0;
        orow[l      ] = T[l      ][o] + bo;   // (65*l+o)%32 = (l+o)%32: conflict-free
        orow[l +  64] = T[l +  64][o] + bo;
        orow[l + 128] = T[l + 128][o] + bo;
        orow[l + 192] = T[l + 192][o] + bo;
    }
}

extern "C" void kernel_launch(void* const* d_in, const int* in_sizes, int n_in,
                              void* d_out, int out_size, void* d_ws, size_t ws_size,
                              hipStream_t stream) {
    const float* features = (const float*)d_in[0];
    const float* theta    = (const float*)d_in[1];
    const float* wbias    = (const float*)d_in[2];
    const int*   nbh      = (const int*)  d_in[3];
    const float* pos      = (const float*)d_in[4];
    const float* bias     = (const float*)d_in[5];
    float* out = (float*)d_out;
    float* ws  = (float*)d_ws;

    const size_t ws_bytes = (size_t)B_ * N_ * COUT_ * sizeof(float);  // 16 MiB
    hipMemsetAsync(ws, 0, ws_bytes, stream);

    flexconv_main<<<B_ * (N_ / 128), 256, 0, stream>>>(features, theta, wbias, nbh, pos, ws);
    flexconv_finish<<<B_ * (N_ / 256), 256, 0, stream>>>(ws, bias, out);
}

// Round 3
// 259.162 us; speedup vs baseline: 1.1100x; 1.1100x over previous
//
#include <hip/hip_runtime.h>

#define B_    4
#define CIN_  64
#define COUT_ 64
#define N_    16384
#define K_    8
#define KN_   (K_ * N_)        // 131072

// ws layout (bytes):
//   counts : [B][N] int      @ 0        (256 KB)
//   offs   : [B][N] int      @ 256 KB
//   cur    : [B][N] int      @ 512 KB
//   entries: [B][K*N] int    @ 768 KB   (2 MB)
//   contrib: [B][K*N][64] f  @ 4 MB     (134.2 MB)
#define WS_OFFS_B    (256u * 1024u)
#define WS_CUR_B     (512u * 1024u)
#define WS_ENT_B     (768u * 1024u)
#define WS_CONTRIB_B (4u * 1024u * 1024u)
#define WS_NEED      ((size_t)WS_CONTRIB_B + (size_t)B_ * KN_ * 64 * 4)

// ---------------------------------------------------------------------------
// CSR build: histogram of targets
// ---------------------------------------------------------------------------
__global__ __launch_bounds__(256) void k_hist(const int* __restrict__ nbh,
                                              int* __restrict__ counts) {
    const int g = blockIdx.x * 256 + threadIdx.x;       // int4 index, 131072 total
    const int4 v = ((const int4*)nbh)[g];
    int* cb = counts + (g >> 15) * N_;                  // (g*4)>>17
    atomicAdd(&cb[v.x], 1);
    atomicAdd(&cb[v.y], 1);
    atomicAdd(&cb[v.z], 1);
    atomicAdd(&cb[v.w], 1);
}

// Exclusive scan per batch (16384 values, 1 block per batch)
__global__ __launch_bounds__(256) void k_scan(const int* __restrict__ counts,
                                              int* __restrict__ offs,
                                              int* __restrict__ cur) {
    __shared__ int P[256];
    const int b = blockIdx.x, t = threadIdx.x;
    const int* cb = counts + b * N_;
    const int base = t * 64;
    int s = 0;
    for (int i = 0; i < 64; ++i) s += cb[base + i];
    P[t] = s;
    __syncthreads();
    for (int d = 1; d < 256; d <<= 1) {
        int v = (t >= d) ? P[t - d] : 0;
        __syncthreads();
        P[t] += v;
        __syncthreads();
    }
    int run = (t == 0) ? 0 : P[t - 1];
    int* ob = offs + b * N_;
    int* ub = cur + b * N_;
    for (int i = 0; i < 64; ++i) {
        const int c = cb[base + i];
        ob[base + i] = run;
        ub[base + i] = run;
        run += c;
    }
}

// Fill: entries[b][p] = k*N+n for each (b,k,n)
__global__ __launch_bounds__(256) void k_fill(const int* __restrict__ nbh,
                                              int* __restrict__ cur,
                                              int* __restrict__ entries) {
    const int g = blockIdx.x * 256 + threadIdx.x;
    const int4 v = ((const int4*)nbh)[g];
    const int b = g >> 15;
    const int r0 = (g << 2) & (KN_ - 1);
    int* ub = cur + b * N_;
    int* eb = entries + (size_t)b * KN_;
    eb[atomicAdd(&ub[v.x], 1)] = r0;
    eb[atomicAdd(&ub[v.y], 1)] = r0 + 1;
    eb[atomicAdd(&ub[v.z], 1)] = r0 + 2;
    eb[atomicAdd(&ub[v.w], 1)] = r0 + 3;
}

// ---------------------------------------------------------------------------
// Dense: per (b, 128-point tile) compute acc[n][o]=(ft0,ft1,ft2,fb), then per
// (n,k) contribution row -> plain store (ATOMIC=false) or atomicAdd fallback.
// ---------------------------------------------------------------------------
template <bool ATOMIC>
__global__ __launch_bounds__(256, 2) void flexconv_dense(
    const float* __restrict__ feat,    // [B, CIN, N]
    const float* __restrict__ theta,   // [3, CIN, COUT]
    const float* __restrict__ wbias,   // [CIN, COUT]
    const int*   __restrict__ nbh,     // [B, K, N]
    const float* __restrict__ pos,     // [B, 3, N]
    float*       __restrict__ dst)     // contrib [B][K*N][64]  or  ws [B][N][64]
{
    __shared__ float4 Wl[CIN_ * COUT_];   // 64 KiB
    __shared__ float  Fl[CIN_ * 64];      // 16 KiB

    const int tid  = threadIdx.x;
    const int lane = tid & 63;            // o
    const int w    = tid >> 6;

    const int b     = blockIdx.x >> 7;
    const int nbase = (blockIdx.x & 127) << 7;

    for (int e = tid; e < CIN_ * COUT_; e += 256) {
        const int i = e >> 6, o = e & 63;
        Wl[e] = make_float4(theta[0 * 4096 + i * 64 + o],
                            theta[1 * 4096 + i * 64 + o],
                            theta[2 * 4096 + i * 64 + o],
                            wbias[i * 64 + o]);
    }

    const float* featb = feat + (size_t)b * CIN_ * N_;
    const float* posb  = pos  + (size_t)b * 3 * N_;
    const int*   nbhb  = nbh  + (size_t)b * KN_;

    for (int t = 0; t < 2; ++t) {
        const int n0 = nbase + t * 64;

        __syncthreads();
        for (int it = 0; it < 4; ++it) {
            const int e = it * 256 + tid;
            const int i = e >> 4, c = e & 15;
            ((float4*)Fl)[i * 16 + c] = *(const float4*)&featb[(size_t)i * N_ + n0 + 4 * c];
        }
        __syncthreads();

        const int pbase = w * 16;
        float4 acc[16];
        #pragma unroll
        for (int j = 0; j < 16; ++j) acc[j] = make_float4(0.f, 0.f, 0.f, 0.f);

        #pragma unroll 2
        for (int i = 0; i < CIN_; ++i) {
            const float4 wv = Wl[i * 64 + lane];
            const float4 f0 = *(const float4*)&Fl[i * 64 + pbase + 0];
            const float4 f1 = *(const float4*)&Fl[i * 64 + pbase + 4];
            const float4 f2 = *(const float4*)&Fl[i * 64 + pbase + 8];
            const float4 f3 = *(const float4*)&Fl[i * 64 + pbase + 12];
            #define ACC1(J, FS) \
                acc[J].x = fmaf(wv.x, FS, acc[J].x); \
                acc[J].y = fmaf(wv.y, FS, acc[J].y); \
                acc[J].z = fmaf(wv.z, FS, acc[J].z); \
                acc[J].w = fmaf(wv.w, FS, acc[J].w);
            ACC1(0,  f0.x) ACC1(1,  f0.y) ACC1(2,  f0.z) ACC1(3,  f0.w)
            ACC1(4,  f1.x) ACC1(5,  f1.y) ACC1(6,  f1.z) ACC1(7,  f1.w)
            ACC1(8,  f2.x) ACC1(9,  f2.y) ACC1(10, f2.z) ACC1(11, f2.w)
            ACC1(12, f3.x) ACC1(13, f3.y) ACC1(14, f3.z) ACC1(15, f3.w)
            #undef ACC1
        }

        #pragma unroll 1
        for (int j = 0; j < 16; ++j) {
            const int n = n0 + pbase + j;
            const float px = posb[n];
            const float py = posb[N_ + n];
            const float pz = posb[2 * N_ + n];
            const float4 a = acc[j];
            #pragma unroll
            for (int k = 0; k < K_; ++k) {
                const int idx = nbhb[k * N_ + n];
                const float dx = posb[idx]          - px;
                const float dy = posb[N_ + idx]     - py;
                const float dz = posb[2 * N_ + idx] - pz;
                const float c  = fmaf(dx, a.x, fmaf(dy, a.y, fmaf(dz, a.z, a.w)));
                if (ATOMIC) {
                    atomicAdd(&dst[((size_t)b * N_ + idx) * 64 + lane], c);
                } else {
                    dst[((size_t)b * KN_ + k * N_ + n) * 64 + lane] = c;  // coalesced 256B
                }
            }
        }
    }
}

// ---------------------------------------------------------------------------
// Reduce: per target j, sum its CSR contribution rows; +bias; transpose-write.
// 64 targets per block (wave handles 16 sequentially).
// ---------------------------------------------------------------------------
__global__ __launch_bounds__(256) void k_reduce(
    const float* __restrict__ contrib,  // [B][K*N][64]
    const int*   __restrict__ offs,     // [B][N]
    const int*   __restrict__ counts,   // [B][N]
    const int*   __restrict__ entries,  // [B][K*N]
    const float* __restrict__ bias,     // [COUT]
    float*       __restrict__ out)      // [B][COUT][N]
{
    __shared__ float T[64][65];
    const int tid  = threadIdx.x;
    const int lane = tid & 63;
    const int w    = tid >> 6;

    const int b  = blockIdx.x >> 8;           // 256 tiles per batch
    const int j0 = (blockIdx.x & 255) << 6;

    const int*   ob = offs    + b * N_;
    const int*   cb = counts  + b * N_;
    const int*   eb = entries + (size_t)b * KN_;
    const float* cr = contrib + (size_t)b * KN_ * 64;

    for (int g = 0; g < 16; ++g) {
        const int jj  = w * 16 + g;
        const int j   = j0 + jj;
        const int off = ob[j];
        const int cnt = cb[j];
        float s0 = 0.f, s1 = 0.f;
        int s = 0;
        for (; s + 2 <= cnt; s += 2) {
            const int e0 = eb[off + s];
            const int e1 = eb[off + s + 1];
            const float c0 = cr[(size_t)e0 * 64 + lane];
            const float c1 = cr[(size_t)e1 * 64 + lane];
            s0 += c0;
            s1 += c1;
        }
        if (s < cnt) {
            const int e0 = eb[off + s];
            s0 += cr[(size_t)e0 * 64 + lane];
        }
        T[jj][lane] = s0 + s1;
    }
    __syncthreads();

    float* outb = out + (size_t)b * COUT_ * N_;
    const int q = w;
    for (int it = 0; it < 16; ++it) {
        const int o  = it * 4 + q;
        outb[(size_t)o * N_ + j0 + lane] = T[lane][o] + bias[o];
    }
}

// Fallback finish (atomic path): out[b][o][n] = ws[b][n][o] + bias[o]
__global__ __launch_bounds__(256) void flexconv_finish(
    const float* __restrict__ ws,
    const float* __restrict__ bias,
    float*       __restrict__ out)
{
    __shared__ float T[64][65];
    const int tid  = threadIdx.x;
    const int lane = tid & 63;
    const int w    = tid >> 6;

    const int b  = blockIdx.x >> 8;
    const int n0 = (blockIdx.x & 255) << 6;

    const float* wsb = ws + (size_t)b * N_ * COUT_;
    for (int r = 0; r < 16; ++r) {
        const int nn = r * 4 + w;
        T[nn][lane] = wsb[(size_t)(n0 + nn) * COUT_ + lane];
    }
    __syncthreads();

    float* outb = out + (size_t)b * COUT_ * N_;
    for (int r = 0; r < 16; ++r) {
        const int o = r * 4 + w;
        outb[(size_t)o * N_ + n0 + lane] = T[lane][o] + bias[o];
    }
}

extern "C" void kernel_launch(void* const* d_in, const int* in_sizes, int n_in,
                              void* d_out, int out_size, void* d_ws, size_t ws_size,
                              hipStream_t stream) {
    const float* features = (const float*)d_in[0];
    const float* theta    = (const float*)d_in[1];
    const float* wbias    = (const float*)d_in[2];
    const int*   nbh      = (const int*)  d_in[3];
    const float* pos      = (const float*)d_in[4];
    const float* bias     = (const float*)d_in[5];
    float* out = (float*)d_out;

    if (ws_size >= WS_NEED) {
        char* wsb = (char*)d_ws;
        int*   counts  = (int*)(wsb);
        int*   offs    = (int*)(wsb + WS_OFFS_B);
        int*   cur     = (int*)(wsb + WS_CUR_B);
        int*   entries = (int*)(wsb + WS_ENT_B);
        float* contrib = (float*)(wsb + WS_CONTRIB_B);

        hipMemsetAsync(counts, 0, (size_t)B_ * N_ * sizeof(int), stream);
        k_hist<<<KN_ * B_ / 1024, 256, 0, stream>>>(nbh, counts);
        k_scan<<<B_, 256, 0, stream>>>(counts, offs, cur);
        k_fill<<<KN_ * B_ / 1024, 256, 0, stream>>>(nbh, cur, entries);
        flexconv_dense<false><<<B_ * (N_ / 128), 256, 0, stream>>>(
            features, theta, wbias, nbh, pos, contrib);
        k_reduce<<<B_ * (N_ / 64), 256, 0, stream>>>(
            contrib, offs, counts, entries, bias, out);
    } else {
        // Fallback: atomic accumulation into ws[b][n][o] (needs 16 MiB)
        float* ws = (float*)d_ws;
        hipMemsetAsync(ws, 0, (size_t)B_ * N_ * COUT_ * sizeof(float), stream);
        flexconv_dense<true><<<B_ * (N_ / 128), 256, 0, stream>>>(
            features, theta, wbias, nbh, pos, ws);
        flexconv_finish<<<B_ * (N_ / 64), 256, 0, stream>>>(ws, bias, out);
    }
}

// Round 5
// 246.891 us; speedup vs baseline: 1.1651x; 1.0497x over previous
//
#include <hip/hip_runtime.h>

#define B_    4
#define CIN_  64
#define COUT_ 64
#define N_    16384
#define K_    8
#define KN_   (K_ * N_)        // 131072

// ws layout (bytes):
//   counts : [B][N] int      @ 0        (256 KB)
//   offs   : [B][N] int      @ 256 KB
//   cur    : [B][N] int      @ 512 KB
//   entries: [B][K*N] int    @ 768 KB   (2 MB)
//   ftT    : [B][N][64] f4   @ 4 MB     (67.1 MB)
#define WS_OFFS_B    (256u * 1024u)
#define WS_CUR_B     (512u * 1024u)
#define WS_ENT_B     (768u * 1024u)
#define WS_FT_B      (4u * 1024u * 1024u)
#define WS_NEED      ((size_t)WS_FT_B + (size_t)B_ * N_ * COUT_ * 4 * sizeof(float))

// ---------------------------------------------------------------------------
// CSR build
// ---------------------------------------------------------------------------
__global__ __launch_bounds__(256) void k_hist(const int* __restrict__ nbh,
                                              int* __restrict__ counts) {
    const int g = blockIdx.x * 256 + threadIdx.x;       // int4 index
    const int4 v = ((const int4*)nbh)[g];
    int* cb = counts + (g >> 15) * N_;
    atomicAdd(&cb[v.x], 1);
    atomicAdd(&cb[v.y], 1);
    atomicAdd(&cb[v.z], 1);
    atomicAdd(&cb[v.w], 1);
}

__global__ __launch_bounds__(256) void k_scan(const int* __restrict__ counts,
                                              int* __restrict__ offs,
                                              int* __restrict__ cur) {
    __shared__ int P[256];
    const int b = blockIdx.x, t = threadIdx.x;
    const int* cb = counts + b * N_;
    const int base = t * 64;
    int s = 0;
    for (int i = 0; i < 64; ++i) s += cb[base + i];
    P[t] = s;
    __syncthreads();
    for (int d = 1; d < 256; d <<= 1) {
        int v = (t >= d) ? P[t - d] : 0;
        __syncthreads();
        P[t] += v;
        __syncthreads();
    }
    int run = (t == 0) ? 0 : P[t - 1];
    int* ob = offs + b * N_;
    int* ub = cur + b * N_;
    for (int i = 0; i < 64; ++i) {
        const int c = cb[base + i];
        ob[base + i] = run;
        ub[base + i] = run;
        run += c;
    }
}

// entries[b][slot] = source point n  (slot from cur[target]++)
__global__ __launch_bounds__(256) void k_fill(const int* __restrict__ nbh,
                                              int* __restrict__ cur,
                                              int* __restrict__ entries) {
    const int g = blockIdx.x * 256 + threadIdx.x;
    const int4 v = ((const int4*)nbh)[g];
    const int b  = g >> 15;
    const int n0 = (g << 2) & (N_ - 1);       // 4 consecutive n, same (b,k)
    int* ub = cur + b * N_;
    int* eb = entries + (size_t)b * KN_;
    eb[atomicAdd(&ub[v.x], 1)] = n0;
    eb[atomicAdd(&ub[v.y], 1)] = n0 + 1;
    eb[atomicAdd(&ub[v.z], 1)] = n0 + 2;
    eb[atomicAdd(&ub[v.w], 1)] = n0 + 3;
}

// ---------------------------------------------------------------------------
// Dense: ftT[b][n][o] = (ft0, ft1, ft2, fb)   (float4 per (n,o), coalesced)
// ---------------------------------------------------------------------------
__global__ __launch_bounds__(256, 2) void flexconv_ft(
    const float* __restrict__ feat,    // [B, CIN, N]
    const float* __restrict__ theta,   // [3, CIN, COUT]
    const float* __restrict__ wbias,   // [CIN, COUT]
    float4*      __restrict__ ftT)     // [B][N][64] float4
{
    __shared__ float4 Wl[CIN_ * COUT_];   // 64 KiB
    __shared__ float  Fl[CIN_ * 64];      // 16 KiB

    const int tid  = threadIdx.x;
    const int lane = tid & 63;            // o
    const int w    = tid >> 6;

    const int b     = blockIdx.x >> 7;
    const int nbase = (blockIdx.x & 127) << 7;

    for (int e = tid; e < CIN_ * COUT_; e += 256) {
        const int i = e >> 6, o = e & 63;
        Wl[e] = make_float4(theta[0 * 4096 + i * 64 + o],
                            theta[1 * 4096 + i * 64 + o],
                            theta[2 * 4096 + i * 64 + o],
                            wbias[i * 64 + o]);
    }

    const float* featb = feat + (size_t)b * CIN_ * N_;
    float4*      ftb   = ftT  + (size_t)b * N_ * 64;

    for (int t = 0; t < 2; ++t) {
        const int n0 = nbase + t * 64;

        __syncthreads();
        for (int it = 0; it < 4; ++it) {
            const int e = it * 256 + tid;
            const int i = e >> 4, c = e & 15;
            ((float4*)Fl)[i * 16 + c] = *(const float4*)&featb[(size_t)i * N_ + n0 + 4 * c];
        }
        __syncthreads();

        const int pbase = w * 16;
        float4 acc[16];
        #pragma unroll
        for (int j = 0; j < 16; ++j) acc[j] = make_float4(0.f, 0.f, 0.f, 0.f);

        #pragma unroll 2
        for (int i = 0; i < CIN_; ++i) {
            const float4 wv = Wl[i * 64 + lane];
            const float4 f0 = *(const float4*)&Fl[i * 64 + pbase + 0];
            const float4 f1 = *(const float4*)&Fl[i * 64 + pbase + 4];
            const float4 f2 = *(const float4*)&Fl[i * 64 + pbase + 8];
            const float4 f3 = *(const float4*)&Fl[i * 64 + pbase + 12];
            #define ACC1(J, FS) \
                acc[J].x = fmaf(wv.x, FS, acc[J].x); \
                acc[J].y = fmaf(wv.y, FS, acc[J].y); \
                acc[J].z = fmaf(wv.z, FS, acc[J].z); \
                acc[J].w = fmaf(wv.w, FS, acc[J].w);
            ACC1(0,  f0.x) ACC1(1,  f0.y) ACC1(2,  f0.z) ACC1(3,  f0.w)
            ACC1(4,  f1.x) ACC1(5,  f1.y) ACC1(6,  f1.z) ACC1(7,  f1.w)
            ACC1(8,  f2.x) ACC1(9,  f2.y) ACC1(10, f2.z) ACC1(11, f2.w)
            ACC1(12, f3.x) ACC1(13, f3.y) ACC1(14, f3.z) ACC1(15, f3.w)
            #undef ACC1
        }

        #pragma unroll
        for (int j = 0; j < 16; ++j) {
            const int n = n0 + pbase + j;
            ftb[(size_t)n * 64 + lane] = acc[j];   // 1 KB/point, coalesced
        }
    }
}

// ---------------------------------------------------------------------------
// Gather: per target j, sum over its CSR sources n_e:
//   c = dx*ft0 + dy*ft1 + dz*ft2 + fb   with delta = pos[j] - pos[n_e]
//   (target minus source — matches reference pos_j - positions)
// 64 targets per block; entry lists staged in LDS (contiguous per block).
// ---------------------------------------------------------------------------
__global__ __launch_bounds__(256) void k_gather(
    const float4* __restrict__ ftT,     // [B][N][64] float4
    const float*  __restrict__ pos,     // [B, 3, N]
    const int*    __restrict__ offs,    // [B][N]
    const int*    __restrict__ counts,  // [B][N]
    const int*    __restrict__ entries, // [B][K*N]
    const float*  __restrict__ bias,    // [COUT]
    float*        __restrict__ out)     // [B][COUT][N]
{
    __shared__ int   E[4096];           // 16 KB entry stage
    __shared__ float T[64][65];         // 16.6 KB transpose tile

    const int tid  = threadIdx.x;
    const int lane = tid & 63;          // o
    const int w    = tid >> 6;

    const int b  = blockIdx.x >> 8;     // 256 tiles per batch
    const int j0 = (blockIdx.x & 255) << 6;

    const int*    ob  = offs    + b * N_;
    const int*    cb  = counts  + b * N_;
    const int*    eb  = entries + (size_t)b * KN_;
    const float4* ftb = ftT     + (size_t)b * N_ * 64;
    const float*  posb = pos    + (size_t)b * 3 * N_;

    const int eLo = ob[j0];
    const int eHi = ob[j0 + 63] + cb[j0 + 63];
    const int range = eHi - eLo;
    const bool staged = (range <= 4096);
    if (staged) {
        for (int e = tid; e < range; e += 256) E[e] = eb[eLo + e];  // coalesced
    }
    __syncthreads();

    for (int g = 0; g < 16; ++g) {
        const int jj  = w * 16 + g;
        const int j   = j0 + jj;
        const int off = ob[j] - eLo;
        const int cnt = cb[j];
        const float px = posb[j];
        const float py = posb[N_ + j];
        const float pz = posb[2 * N_ + j];

        float s0 = 0.f, s1 = 0.f;
        int s = 0;
        if (staged) {
            for (; s + 2 <= cnt; s += 2) {
                const int n0e = E[off + s];
                const int n1e = E[off + s + 1];
                const float4 f0 = ftb[(size_t)n0e * 64 + lane];
                const float4 f1 = ftb[(size_t)n1e * 64 + lane];
                s0 += fmaf(px - posb[n0e], f0.x,
                      fmaf(py - posb[N_ + n0e], f0.y,
                      fmaf(pz - posb[2 * N_ + n0e], f0.z, f0.w)));
                s1 += fmaf(px - posb[n1e], f1.x,
                      fmaf(py - posb[N_ + n1e], f1.y,
                      fmaf(pz - posb[2 * N_ + n1e], f1.z, f1.w)));
            }
            if (s < cnt) {
                const int ne = E[off + s];
                const float4 f = ftb[(size_t)ne * 64 + lane];
                s0 += fmaf(px - posb[ne], f.x,
                      fmaf(py - posb[N_ + ne], f.y,
                      fmaf(pz - posb[2 * N_ + ne], f.z, f.w)));
            }
        } else {
            for (; s < cnt; ++s) {
                const int ne = eb[eLo + off + s];
                const float4 f = ftb[(size_t)ne * 64 + lane];
                s0 += fmaf(px - posb[ne], f.x,
                      fmaf(py - posb[N_ + ne], f.y,
                      fmaf(pz - posb[2 * N_ + ne], f.z, f.w)));
            }
        }
        T[jj][lane] = s0 + s1;
    }
    __syncthreads();

    float* outb = out + (size_t)b * COUT_ * N_;
    for (int it = 0; it < 16; ++it) {
        const int o = it * 4 + w;
        outb[(size_t)o * N_ + j0 + lane] = T[lane][o] + bias[o];  // coalesced
    }
}

// ---------------------------------------------------------------------------
// Fallback (small ws): atomic scatter into ws[b][n][o] + transpose finish
// ---------------------------------------------------------------------------
__global__ __launch_bounds__(256, 2) void flexconv_atomic(
    const float* __restrict__ feat, const float* __restrict__ theta,
    const float* __restrict__ wbias, const int* __restrict__ nbh,
    const float* __restrict__ pos, float* __restrict__ ws)
{
    __shared__ float4 Wl[CIN_ * COUT_];
    __shared__ float  Fl[CIN_ * 64];
    const int tid = threadIdx.x, lane = tid & 63, w = tid >> 6;
    const int b = blockIdx.x >> 7, nbase = (blockIdx.x & 127) << 7;
    for (int e = tid; e < CIN_ * COUT_; e += 256) {
        const int i = e >> 6, o = e & 63;
        Wl[e] = make_float4(theta[i * 64 + o], theta[4096 + i * 64 + o],
                            theta[8192 + i * 64 + o], wbias[i * 64 + o]);
    }
    const float* featb = feat + (size_t)b * CIN_ * N_;
    const float* posb  = pos  + (size_t)b * 3 * N_;
    const int*   nbhb  = nbh  + (size_t)b * KN_;
    float*       wsb   = ws   + (size_t)b * N_ * COUT_;
    for (int t = 0; t < 2; ++t) {
        const int n0 = nbase + t * 64;
        __syncthreads();
        for (int it = 0; it < 4; ++it) {
            const int e = it * 256 + tid, i = e >> 4, c = e & 15;
            ((float4*)Fl)[i * 16 + c] = *(const float4*)&featb[(size_t)i * N_ + n0 + 4 * c];
        }
        __syncthreads();
        const int pbase = w * 16;
        float4 acc[16];
        #pragma unroll
        for (int j = 0; j < 16; ++j) acc[j] = make_float4(0.f, 0.f, 0.f, 0.f);
        for (int i = 0; i < CIN_; ++i) {
            const float4 wv = Wl[i * 64 + lane];
            #pragma unroll
            for (int j = 0; j < 16; ++j) {
                const float fs = Fl[i * 64 + pbase + j];
                acc[j].x = fmaf(wv.x, fs, acc[j].x);
                acc[j].y = fmaf(wv.y, fs, acc[j].y);
                acc[j].z = fmaf(wv.z, fs, acc[j].z);
                acc[j].w = fmaf(wv.w, fs, acc[j].w);
            }
        }
        for (int j = 0; j < 16; ++j) {
            const int n = n0 + pbase + j;
            const float px = posb[n], py = posb[N_ + n], pz = posb[2 * N_ + n];
            const float4 a = acc[j];
            for (int k = 0; k < K_; ++k) {
                const int idx = nbhb[k * N_ + n];
                const float c = fmaf(posb[idx] - px, a.x,
                               fmaf(posb[N_ + idx] - py, a.y,
                               fmaf(posb[2 * N_ + idx] - pz, a.z, a.w)));
                atomicAdd(&wsb[(size_t)idx * COUT_ + lane], c);
            }
        }
    }
}

__global__ __launch_bounds__(256) void flexconv_finish(
    const float* __restrict__ ws, const float* __restrict__ bias,
    float* __restrict__ out)
{
    __shared__ float T[64][65];
    const int tid = threadIdx.x, lane = tid & 63, w = tid >> 6;
    const int b = blockIdx.x >> 8, n0 = (blockIdx.x & 255) << 6;
    const float* wsb = ws + (size_t)b * N_ * COUT_;
    for (int r = 0; r < 16; ++r) {
        const int nn = r * 4 + w;
        T[nn][lane] = wsb[(size_t)(n0 + nn) * COUT_ + lane];
    }
    __syncthreads();
    float* outb = out + (size_t)b * COUT_ * N_;
    for (int r = 0; r < 16; ++r) {
        const int o = r * 4 + w;
        outb[(size_t)o * N_ + n0 + lane] = T[lane][o] + bias[o];
    }
}

extern "C" void kernel_launch(void* const* d_in, const int* in_sizes, int n_in,
                              void* d_out, int out_size, void* d_ws, size_t ws_size,
                              hipStream_t stream) {
    const float* features = (const float*)d_in[0];
    const float* theta    = (const float*)d_in[1];
    const float* wbias    = (const float*)d_in[2];
    const int*   nbh      = (const int*)  d_in[3];
    const float* pos      = (const float*)d_in[4];
    const float* bias     = (const float*)d_in[5];
    float* out = (float*)d_out;

    if (ws_size >= WS_NEED) {
        char* wsb = (char*)d_ws;
        int*    counts  = (int*)(wsb);
        int*    offs    = (int*)(wsb + WS_OFFS_B);
        int*    cur     = (int*)(wsb + WS_CUR_B);
        int*    entries = (int*)(wsb + WS_ENT_B);
        float4* ftT     = (float4*)(wsb + WS_FT_B);

        hipMemsetAsync(counts, 0, (size_t)B_ * N_ * sizeof(int), stream);
        k_hist<<<KN_ * B_ / 1024, 256, 0, stream>>>(nbh, counts);
        k_scan<<<B_, 256, 0, stream>>>(counts, offs, cur);
        k_fill<<<KN_ * B_ / 1024, 256, 0, stream>>>(nbh, cur, entries);
        flexconv_ft<<<B_ * (N_ / 128), 256, 0, stream>>>(features, theta, wbias, ftT);
        k_gather<<<B_ * (N_ / 64), 256, 0, stream>>>(
            ftT, pos, offs, counts, entries, bias, out);
    } else {
        float* ws = (float*)d_ws;
        hipMemsetAsync(ws, 0, (size_t)B_ * N_ * COUT_ * sizeof(float), stream);
        flexconv_atomic<<<B_ * (N_ / 128), 256, 0, stream>>>(
            features, theta, wbias, nbh, pos, ws);
        flexconv_finish<<<B_ * (N_ / 64), 256, 0, stream>>>(ws, bias, out);
    }
}

// Round 6
// 244.839 us; speedup vs baseline: 1.1749x; 1.0084x over previous
//
#include <hip/hip_runtime.h>

#define B_    4
#define CIN_  64
#define COUT_ 64
#define N_    16384
#define K_    8
#define KN_   (K_ * N_)        // 131072

// ws layout (bytes):
//   counts : [B][N] int        @ 0        (256 KB)
//   offs   : [B][N] int        @ 256 KB
//   entries: [B][K*N] int      @ 768 KB   (2 MB)
//   ftT    : [B][N][64] u16x4  @ 4 MB     (33.6 MB)
#define WS_OFFS_B    (256u * 1024u)
#define WS_ENT_B     (768u * 1024u)
#define WS_FT_B      (4u * 1024u * 1024u)
#define WS_NEED      ((size_t)WS_FT_B + (size_t)B_ * N_ * COUT_ * 4 * sizeof(unsigned short))

static __device__ __forceinline__ unsigned short f2bf(float f) {
    union { float f; unsigned int u; } c; c.f = f;
    unsigned int u = c.u;
    u += 0x7FFFu + ((u >> 16) & 1u);          // round-to-nearest-even
    return (unsigned short)(u >> 16);
}
static __device__ __forceinline__ float bf2f(unsigned short h) {
    union { unsigned int u; float f; } c; c.u = ((unsigned int)h) << 16;
    return c.f;
}

// ---------------------------------------------------------------------------
// Fused CSR build: one block per batch. LDS histogram -> LDS scan -> fill.
// ---------------------------------------------------------------------------
#define CSR_T 1024
__global__ __launch_bounds__(CSR_T) void k_csr(
    const int* __restrict__ nbh,       // [B][K*N]
    int* __restrict__ offs,            // [B][N]
    int* __restrict__ counts,          // [B][N]
    int* __restrict__ entries)         // [B][K*N]
{
    __shared__ int cnt[N_];            // 64 KB
    __shared__ int P[CSR_T];           // 4 KB

    const int t = threadIdx.x, b = blockIdx.x;
    const int4* nb4 = (const int4*)(nbh + (size_t)b * KN_);

    // zero histogram
    #pragma unroll
    for (int i = 0; i < N_ / CSR_T; ++i) cnt[i * CSR_T + t] = 0;
    __syncthreads();

    // histogram (LDS atomics)
    #pragma unroll 4
    for (int it = 0; it < KN_ / 4 / CSR_T; ++it) {       // 32 iters
        const int4 v = nb4[it * CSR_T + t];
        atomicAdd(&cnt[v.x], 1);
        atomicAdd(&cnt[v.y], 1);
        atomicAdd(&cnt[v.z], 1);
        atomicAdd(&cnt[v.w], 1);
    }
    __syncthreads();

    // scan: per-thread partial over 16 consecutive, then Hillis-Steele over 1024
    const int base = t * 16;
    int s = 0;
    #pragma unroll
    for (int i = 0; i < 16; ++i) s += cnt[base + i];
    P[t] = s;
    __syncthreads();
    for (int d = 1; d < CSR_T; d <<= 1) {
        int v = (t >= d) ? P[t - d] : 0;
        __syncthreads();
        P[t] += v;
        __syncthreads();
    }
    int run = (t > 0) ? P[t - 1] : 0;

    int* ob = offs   + b * N_;
    int* cb = counts + b * N_;
    #pragma unroll
    for (int i = 0; i < 16; ++i) {
        const int c = cnt[base + i];
        ob[base + i]  = run;
        cb[base + i]  = c;
        cnt[base + i] = run;           // repurpose as cursor
        run += c;
    }
    __syncthreads();

    // fill: slot from LDS cursor, entries[slot] = source n
    int* eb = entries + (size_t)b * KN_;
    #pragma unroll 4
    for (int it = 0; it < KN_ / 4 / CSR_T; ++it) {
        const int idx = it * CSR_T + t;            // int4 index
        const int4 v = nb4[idx];
        const int n0 = (idx << 2) & (N_ - 1);      // 4 consecutive n, same k-row
        eb[atomicAdd(&cnt[v.x], 1)] = n0;
        eb[atomicAdd(&cnt[v.y], 1)] = n0 + 1;
        eb[atomicAdd(&cnt[v.z], 1)] = n0 + 2;
        eb[atomicAdd(&cnt[v.w], 1)] = n0 + 3;
    }
}

// ---------------------------------------------------------------------------
// Dense: ftT[b][n][o] = bf16x4(ft0, ft1, ft2, fb)   (512 B/point, coalesced)
// ---------------------------------------------------------------------------
__global__ __launch_bounds__(256, 2) void flexconv_ft(
    const float* __restrict__ feat,    // [B, CIN, N]
    const float* __restrict__ theta,   // [3, CIN, COUT]
    const float* __restrict__ wbias,   // [CIN, COUT]
    ushort4*     __restrict__ ftT)     // [B][N][64]
{
    __shared__ float4 Wl[CIN_ * COUT_];   // 64 KiB
    __shared__ float  Fl[CIN_ * 64];      // 16 KiB

    const int tid  = threadIdx.x;
    const int lane = tid & 63;            // o
    const int w    = tid >> 6;

    const int b     = blockIdx.x >> 7;
    const int nbase = (blockIdx.x & 127) << 7;

    for (int e = tid; e < CIN_ * COUT_; e += 256) {
        const int i = e >> 6, o = e & 63;
        Wl[e] = make_float4(theta[0 * 4096 + i * 64 + o],
                            theta[1 * 4096 + i * 64 + o],
                            theta[2 * 4096 + i * 64 + o],
                            wbias[i * 64 + o]);
    }

    const float* featb = feat + (size_t)b * CIN_ * N_;
    ushort4*     ftb   = ftT  + (size_t)b * N_ * 64;

    for (int t = 0; t < 2; ++t) {
        const int n0 = nbase + t * 64;

        __syncthreads();
        for (int it = 0; it < 4; ++it) {
            const int e = it * 256 + tid;
            const int i = e >> 4, c = e & 15;
            ((float4*)Fl)[i * 16 + c] = *(const float4*)&featb[(size_t)i * N_ + n0 + 4 * c];
        }
        __syncthreads();

        const int pbase = w * 16;
        float4 acc[16];
        #pragma unroll
        for (int j = 0; j < 16; ++j) acc[j] = make_float4(0.f, 0.f, 0.f, 0.f);

        #pragma unroll 2
        for (int i = 0; i < CIN_; ++i) {
            const float4 wv = Wl[i * 64 + lane];
            const float4 f0 = *(const float4*)&Fl[i * 64 + pbase + 0];
            const float4 f1 = *(const float4*)&Fl[i * 64 + pbase + 4];
            const float4 f2 = *(const float4*)&Fl[i * 64 + pbase + 8];
            const float4 f3 = *(const float4*)&Fl[i * 64 + pbase + 12];
            #define ACC1(J, FS) \
                acc[J].x = fmaf(wv.x, FS, acc[J].x); \
                acc[J].y = fmaf(wv.y, FS, acc[J].y); \
                acc[J].z = fmaf(wv.z, FS, acc[J].z); \
                acc[J].w = fmaf(wv.w, FS, acc[J].w);
            ACC1(0,  f0.x) ACC1(1,  f0.y) ACC1(2,  f0.z) ACC1(3,  f0.w)
            ACC1(4,  f1.x) ACC1(5,  f1.y) ACC1(6,  f1.z) ACC1(7,  f1.w)
            ACC1(8,  f2.x) ACC1(9,  f2.y) ACC1(10, f2.z) ACC1(11, f2.w)
            ACC1(12, f3.x) ACC1(13, f3.y) ACC1(14, f3.z) ACC1(15, f3.w)
            #undef ACC1
        }

        #pragma unroll
        for (int j = 0; j < 16; ++j) {
            const int n = n0 + pbase + j;
            ushort4 h;
            h.x = f2bf(acc[j].x);
            h.y = f2bf(acc[j].y);
            h.z = f2bf(acc[j].z);
            h.w = f2bf(acc[j].w);
            ftb[(size_t)n * 64 + lane] = h;        // 512 B/point, coalesced
        }
    }
}

// ---------------------------------------------------------------------------
// Gather: per target j, c = dx*ft0 + dy*ft1 + dz*ft2 + fb, delta = pos[j]-pos[src]
// 64 targets per block; entry lists staged in LDS; unroll 4 for MLP.
// ---------------------------------------------------------------------------
#define GATH1(SACC, NE) { \
    const int ne_ = (NE); \
    const ushort4 h_ = ftb[(size_t)ne_ * 64 + lane]; \
    SACC += fmaf(px - posb[ne_], bf2f(h_.x), \
            fmaf(py - posb[N_ + ne_], bf2f(h_.y), \
            fmaf(pz - posb[2 * N_ + ne_], bf2f(h_.z), bf2f(h_.w)))); }

__global__ __launch_bounds__(256) void k_gather(
    const ushort4* __restrict__ ftT,     // [B][N][64]
    const float*   __restrict__ pos,     // [B, 3, N]
    const int*     __restrict__ offs,    // [B][N]
    const int*     __restrict__ counts,  // [B][N]
    const int*     __restrict__ entries, // [B][K*N]
    const float*   __restrict__ bias,    // [COUT]
    float*         __restrict__ out)     // [B][COUT][N]
{
    __shared__ int   E[4096];           // 16 KB entry stage
    __shared__ float T[64][65];         // 16.6 KB transpose tile

    const int tid  = threadIdx.x;
    const int lane = tid & 63;          // o
    const int w    = tid >> 6;

    const int b  = blockIdx.x >> 8;     // 256 tiles per batch
    const int j0 = (blockIdx.x & 255) << 6;

    const int*     ob   = offs    + b * N_;
    const int*     cb   = counts  + b * N_;
    const int*     eb   = entries + (size_t)b * KN_;
    const ushort4* ftb  = ftT     + (size_t)b * N_ * 64;
    const float*   posb = pos     + (size_t)b * 3 * N_;

    const int eLo = ob[j0];
    const int eHi = ob[j0 + 63] + cb[j0 + 63];
    const int range = eHi - eLo;
    const bool staged = (range <= 4096);
    if (staged) {
        for (int e = tid; e < range; e += 256) E[e] = eb[eLo + e];  // coalesced
    }
    __syncthreads();

    for (int g = 0; g < 16; ++g) {
        const int jj  = w * 16 + g;
        const int j   = j0 + jj;
        const int off = ob[j] - eLo;
        const int cnt = cb[j];
        const float px = posb[j];
        const float py = posb[N_ + j];
        const float pz = posb[2 * N_ + j];

        float s0 = 0.f, s1 = 0.f, s2 = 0.f, s3 = 0.f;
        int s = 0;
        if (staged) {
            for (; s + 4 <= cnt; s += 4) {
                const int e0 = E[off + s];
                const int e1 = E[off + s + 1];
                const int e2 = E[off + s + 2];
                const int e3 = E[off + s + 3];
                GATH1(s0, e0)
                GATH1(s1, e1)
                GATH1(s2, e2)
                GATH1(s3, e3)
            }
            for (; s < cnt; ++s) GATH1(s0, E[off + s])
        } else {
            for (; s < cnt; ++s) GATH1(s0, eb[eLo + off + s])
        }
        T[jj][lane] = (s0 + s1) + (s2 + s3);
    }
    __syncthreads();

    float* outb = out + (size_t)b * COUT_ * N_;
    for (int it = 0; it < 16; ++it) {
        const int o = it * 4 + w;
        outb[(size_t)o * N_ + j0 + lane] = T[lane][o] + bias[o];  // coalesced
    }
}

// ---------------------------------------------------------------------------
// Fallback (small ws): atomic scatter into ws[b][n][o] + transpose finish
// ---------------------------------------------------------------------------
__global__ __launch_bounds__(256, 2) void flexconv_atomic(
    const float* __restrict__ feat, const float* __restrict__ theta,
    const float* __restrict__ wbias, const int* __restrict__ nbh,
    const float* __restrict__ pos, float* __restrict__ ws)
{
    __shared__ float4 Wl[CIN_ * COUT_];
    __shared__ float  Fl[CIN_ * 64];
    const int tid = threadIdx.x, lane = tid & 63, w = tid >> 6;
    const int b = blockIdx.x >> 7, nbase = (blockIdx.x & 127) << 7;
    for (int e = tid; e < CIN_ * COUT_; e += 256) {
        const int i = e >> 6, o = e & 63;
        Wl[e] = make_float4(theta[i * 64 + o], theta[4096 + i * 64 + o],
                            theta[8192 + i * 64 + o], wbias[i * 64 + o]);
    }
    const float* featb = feat + (size_t)b * CIN_ * N_;
    const float* posb  = pos  + (size_t)b * 3 * N_;
    const int*   nbhb  = nbh  + (size_t)b * KN_;
    float*       wsb   = ws   + (size_t)b * N_ * COUT_;
    for (int t = 0; t < 2; ++t) {
        const int n0 = nbase + t * 64;
        __syncthreads();
        for (int it = 0; it < 4; ++it) {
            const int e = it * 256 + tid, i = e >> 4, c = e & 15;
            ((float4*)Fl)[i * 16 + c] = *(const float4*)&featb[(size_t)i * N_ + n0 + 4 * c];
        }
        __syncthreads();
        const int pbase = w * 16;
        float4 acc[16];
        #pragma unroll
        for (int j = 0; j < 16; ++j) acc[j] = make_float4(0.f, 0.f, 0.f, 0.f);
        for (int i = 0; i < CIN_; ++i) {
            const float4 wv = Wl[i * 64 + lane];
            #pragma unroll
            for (int j = 0; j < 16; ++j) {
                const float fs = Fl[i * 64 + pbase + j];
                acc[j].x = fmaf(wv.x, fs, acc[j].x);
                acc[j].y = fmaf(wv.y, fs, acc[j].y);
                acc[j].z = fmaf(wv.z, fs, acc[j].z);
                acc[j].w = fmaf(wv.w, fs, acc[j].w);
            }
        }
        for (int j = 0; j < 16; ++j) {
            const int n = n0 + pbase + j;
            const float px = posb[n], py = posb[N_ + n], pz = posb[2 * N_ + n];
            const float4 a = acc[j];
            for (int k = 0; k < K_; ++k) {
                const int idx = nbhb[k * N_ + n];
                const float c = fmaf(posb[idx] - px, a.x,
                               fmaf(posb[N_ + idx] - py, a.y,
                               fmaf(posb[2 * N_ + idx] - pz, a.z, a.w)));
                atomicAdd(&wsb[(size_t)idx * COUT_ + lane], c);
            }
        }
    }
}

__global__ __launch_bounds__(256) void flexconv_finish(
    const float* __restrict__ ws, const float* __restrict__ bias,
    float* __restrict__ out)
{
    __shared__ float T[64][65];
    const int tid = threadIdx.x, lane = tid & 63, w = tid >> 6;
    const int b = blockIdx.x >> 8, n0 = (blockIdx.x & 255) << 6;
    const float* wsb = ws + (size_t)b * N_ * COUT_;
    for (int r = 0; r < 16; ++r) {
        const int nn = r * 4 + w;
        T[nn][lane] = wsb[(size_t)(n0 + nn) * COUT_ + lane];
    }
    __syncthreads();
    float* outb = out + (size_t)b * COUT_ * N_;
    for (int r = 0; r < 16; ++r) {
        const int o = r * 4 + w;
        outb[(size_t)o * N_ + n0 + lane] = T[lane][o] + bias[o];
    }
}

extern "C" void kernel_launch(void* const* d_in, const int* in_sizes, int n_in,
                              void* d_out, int out_size, void* d_ws, size_t ws_size,
                              hipStream_t stream) {
    const float* features = (const float*)d_in[0];
    const float* theta    = (const float*)d_in[1];
    const float* wbias    = (const float*)d_in[2];
    const int*   nbh      = (const int*)  d_in[3];
    const float* pos      = (const float*)d_in[4];
    const float* bias     = (const float*)d_in[5];
    float* out = (float*)d_out;

    if (ws_size >= WS_NEED) {
        char* wsb = (char*)d_ws;
        int*     counts  = (int*)(wsb);
        int*     offs    = (int*)(wsb + WS_OFFS_B);
        int*     entries = (int*)(wsb + WS_ENT_B);
        ushort4* ftT     = (ushort4*)(wsb + WS_FT_B);

        k_csr<<<B_, CSR_T, 0, stream>>>(nbh, offs, counts, entries);
        flexconv_ft<<<B_ * (N_ / 128), 256, 0, stream>>>(features, theta, wbias, ftT);
        k_gather<<<B_ * (N_ / 64), 256, 0, stream>>>(
            ftT, pos, offs, counts, entries, bias, out);
    } else {
        float* ws = (float*)d_ws;
        hipMemsetAsync(ws, 0, (size_t)B_ * N_ * COUT_ * sizeof(float), stream);
        flexconv_atomic<<<B_ * (N_ / 128), 256, 0, stream>>>(
            features, theta, wbias, nbh, pos, ws);
        flexconv_finish<<<B_ * (N_ / 64), 256, 0, stream>>>(ws, bias, out);
    }
}